// Round 1
// baseline (390.087 us; speedup 1.0000x reference)
//
#include <hip/hip_runtime.h>
#include <hip/hip_bf16.h>

typedef __bf16 bf16_t;
typedef __bf16 bf16x4 __attribute__((ext_vector_type(4)));
typedef __bf16 bf16x8 __attribute__((ext_vector_type(8)));
typedef float  f32x4  __attribute__((ext_vector_type(4)));

static __device__ __forceinline__ f32x4 mfma16(bf16x8 a, bf16x8 b, f32x4 c) {
  return __builtin_amdgcn_mfma_f32_16x16x32_bf16(a, b, c, 0, 0, 0);
}

typedef const __attribute__((address_space(1))) void* gas_t;
typedef __attribute__((address_space(3))) void* las_t;
#define ASYNC16(g, l) __builtin_amdgcn_global_load_lds((gas_t)(g), (las_t)(l), 16, 0, 0)

// Problem constants
#define QL_   512
#define HID_  4096
#define NH_   32
#define NKV_  8
#define HD_   128
#define PAST_ 3584
#define KVL_  4096   // PAST_ + QL_
#define NSPLIT 8     // attention kv-split factor

// Q prescale: log2(e)/sqrt(128) -> softmax via raw exp2, no max subtraction
#define QSCALE 0.12751750152134056f

// K fragment-layout index (kv-tiles of 64, MFMA B-operand contiguous)
static __device__ __forceinline__ size_t kidx(int s, int d) {
  return ((size_t)(((s >> 6) * 4 + ((s >> 4) & 3)) * 4 + (d >> 5))) * 512
         + ((((d >> 3) & 3) * 16 + (s & 15)) * 8) + (d & 7);
}
// V fragment-layout index (PV B-operand: out-col = d, contraction = kv)
static __device__ __forceinline__ size_t vidx(int s, int d) {
  return ((size_t)(((s >> 6) * 8 + (d >> 4)) * 2 + ((s >> 5) & 1))) * 512
         + (((((s >> 3) & 3) * 16 + (d & 15)) * 8)) + (s & 7);
}

static __device__ __forceinline__ bf16x8 cvt8(float4 a, float4 b) {
  bf16x8 o;
  o[0] = (bf16_t)a.x; o[1] = (bf16_t)a.y; o[2] = (bf16_t)a.z; o[3] = (bf16_t)a.w;
  o[4] = (bf16_t)b.x; o[5] = (bf16_t)b.y; o[6] = (bf16_t)b.z; o[7] = (bf16_t)b.w;
  return o;
}

// ======================================================================
// fp32 -> bf16 streaming convert (n4 = element count / 4)
// ======================================================================
__global__ __launch_bounds__(256) void cvt_f32_bf16(
    const float* __restrict__ src, bf16_t* __restrict__ dst, int n4)
{
  int i = blockIdx.x * 256 + threadIdx.x;
  const int stride = gridDim.x * 256;
  for (; i < n4; i += stride) {
    float4 f = ((const float4*)src)[i];
    bf16x4 o;
    o[0] = (bf16_t)f.x; o[1] = (bf16_t)f.y; o[2] = (bf16_t)f.z; o[3] = (bf16_t)f.w;
    ((bf16x4*)dst)[i] = o;
  }
}

// ======================================================================
// GEMM: C[M,N] = A[M,K] @ B[N,K]^T.  A bf16 (global_load_lds),
// B fp32 converted inline during reg-staging (saves the standalone
// weight-cvt kernels: 240 MB of HBM traffic per launch).
// BM=BN=64, BK=64; 4 waves 2x2, double-buffered.
// B global loads issued BEFORE the A ASYNC16s so the pre-barrier
// ds_write waits at vmcnt(2), not vmcnt(0).
// ======================================================================
template<bool C_F32>
__global__ __launch_bounds__(256) void gemm_bt(
    const bf16_t* __restrict__ A,
    const float* __restrict__ B0, const float* __restrict__ B1,
    const float* __restrict__ B2, int nsplit1, int nsplit2,
    void* __restrict__ Cptr, int K, int lda, int ldb, int ldc)
{
  constexpr int BM = 64, BN = 64, BK = 64;
  __shared__ bf16_t As[2][BM * BK];
  __shared__ bf16_t Bs[2][BN * BK];

  const int tid = threadIdx.x;
  const int w = tid >> 6, lane = tid & 63;
  const int lm = lane & 15, quad = lane >> 4;
  const int wr = w >> 1, wc = w & 1;
  const int bm0 = blockIdx.y * BM, bn0 = blockIdx.x * BN;

  const float* Bseg; int bn_loc;
  if (bn0 < nsplit1)      { Bseg = B0; bn_loc = bn0; }
  else if (bn0 < nsplit2) { Bseg = B1; bn_loc = bn0 - nsplit1; }
  else                    { Bseg = B2; bn_loc = bn0 - nsplit2; }

  int sid[2], soff[2];
#pragma unroll
  for (int j = 0; j < 2; j++) {
    sid[j] = j * 256 + tid;
    const int r = sid[j] >> 3, c = sid[j] & 7;
    soff[j] = r * 64 + (c ^ (r & 7)) * 8;
  }
  const bf16_t* Abase = A + (size_t)bm0 * lda;
  const float* Bbase = Bseg + (size_t)bn_loc * ldb;

  f32x4 acc[2][2];
#pragma unroll
  for (int i = 0; i < 2; i++)
#pragma unroll
    for (int j = 0; j < 2; j++) acc[i][j] = f32x4{0.f, 0.f, 0.f, 0.f};

  float4 bB[2][2];
  // prologue: stage tile 0 (B via regs+cvt, A via global_load_lds)
#pragma unroll
  for (int j = 0; j < 2; j++) {
    const int r = soff[j] >> 6, c = soff[j] & 63;
    const float* bp = Bbase + (size_t)r * ldb + c;
    bB[j][0] = *(const float4*)bp;
    bB[j][1] = *(const float4*)(bp + 4);
  }
#pragma unroll
  for (int j = 0; j < 2; j++) {
    const int r = soff[j] >> 6, c = soff[j] & 63;
    ASYNC16(Abase + (size_t)r * lda + c, &As[0][sid[j] * 8]);
  }
#pragma unroll
  for (int j = 0; j < 2; j++)
    *(bf16x8*)&Bs[0][sid[j] * 8] = cvt8(bB[j][0], bB[j][1]);

  int cur = 0;
  for (int k0 = 0; k0 < K; k0 += BK) {
    __syncthreads();
    const bool pre = (k0 + BK < K);
    if (pre) {
#pragma unroll
      for (int j = 0; j < 2; j++) {
        const int r = soff[j] >> 6, c = soff[j] & 63;
        const float* bp = Bbase + (size_t)r * ldb + k0 + BK + c;
        bB[j][0] = *(const float4*)bp;
        bB[j][1] = *(const float4*)(bp + 4);
      }
#pragma unroll
      for (int j = 0; j < 2; j++) {
        const int r = soff[j] >> 6, c = soff[j] & 63;
        ASYNC16(Abase + (size_t)r * lda + k0 + BK + c, &As[cur ^ 1][sid[j] * 8]);
      }
    }
#pragma unroll
    for (int kb = 0; kb < 2; kb++) {
      bf16x8 af[2], bf[2];
#pragma unroll
      for (int mt = 0; mt < 2; mt++) {
        const int r = wr * 32 + mt * 16 + lm;
        af[mt] = *(const bf16x8*)&As[cur][r * 64 + (((kb * 4 + quad) ^ (r & 7)) * 8)];
      }
#pragma unroll
      for (int nt = 0; nt < 2; nt++) {
        const int r = wc * 32 + nt * 16 + lm;
        bf[nt] = *(const bf16x8*)&Bs[cur][r * 64 + (((kb * 4 + quad) ^ (r & 7)) * 8)];
      }
#pragma unroll
      for (int mt = 0; mt < 2; mt++)
#pragma unroll
        for (int nt = 0; nt < 2; nt++)
          acc[mt][nt] = mfma16(af[mt], bf[nt], acc[mt][nt]);
    }
    if (pre) {
#pragma unroll
      for (int j = 0; j < 2; j++)
        *(bf16x8*)&Bs[cur ^ 1][sid[j] * 8] = cvt8(bB[j][0], bB[j][1]);
    }
    cur ^= 1;
  }

#pragma unroll
  for (int mt = 0; mt < 2; mt++) {
#pragma unroll
    for (int nt = 0; nt < 2; nt++) {
      const int row = bm0 + wr * 32 + mt * 16 + quad * 4;
      const int col = bn0 + wc * 32 + nt * 16 + lm;
#pragma unroll
      for (int r = 0; r < 4; r++) {
        if constexpr (C_F32)
          ((float*)Cptr)[(size_t)(row + r) * ldc + col] = acc[mt][nt][r];
        else
          ((bf16_t*)Cptr)[(size_t)(row + r) * ldc + col] = (bf16_t)acc[mt][nt][r];
      }
    }
  }
}

// ======================================================================
// Dequant past K -> fragment-contiguous Kc.
// ======================================================================
__global__ __launch_bounds__(128) void dequant_key(
    const float* __restrict__ pk, bf16_t* __restrict__ Kc)
{
  const int g = blockIdx.x, h = blockIdx.y, d = threadIdx.x;
  const float* src = pk + ((size_t)h * PAST_ + g * 32) * HD_ + d;
  float x[32];
  float mn = 1e30f, mx = -1e30f;
#pragma unroll
  for (int s = 0; s < 32; s++) {
    x[s] = src[(size_t)s * HD_];
    mn = fminf(mn, x[s]); mx = fmaxf(mx, x[s]);
  }
  float scale = (mx - mn) / 15.0f;
  bf16_t* dst = Kc + (size_t)h * (KVL_ * HD_);
#pragma unroll
  for (int s = 0; s < 32; s++) {
    float t = scale > 0.f ? (x[s] - mn) / scale : 0.f;
    float q = fminf(fmaxf(rintf(t), 0.f), 15.f);
    dst[kidx(g * 32 + s, d)] = (bf16_t)(q * scale + mn);
  }
}

// ======================================================================
// Dequant past V -> fragment-contiguous Vc.
// ======================================================================
__global__ __launch_bounds__(256) void dequant_value(
    const float* __restrict__ pv, bf16_t* __restrict__ Vc)
{
  const int sc = blockIdx.x, h = blockIdx.y;
  const int j = threadIdx.x >> 6, lane = threadIdx.x & 63;
  const int s = sc * 64 + lane;
  const float* src = pv + ((size_t)h * PAST_ + s) * HD_ + j * 32;
  float x[32];
  float mn = 1e30f, mx = -1e30f;
#pragma unroll
  for (int q4 = 0; q4 < 8; q4++) {
    float4 f = ((const float4*)src)[q4];
    x[q4*4+0] = f.x; x[q4*4+1] = f.y; x[q4*4+2] = f.z; x[q4*4+3] = f.w;
    mn = fminf(fminf(mn, fminf(f.x, f.y)), fminf(f.z, f.w));
    mx = fmaxf(fmaxf(mx, fmaxf(f.x, f.y)), fmaxf(f.z, f.w));
  }
  float scale = (mx - mn) / 15.0f;
  bf16_t* dst = Vc + (size_t)h * (KVL_ * HD_);
#pragma unroll
  for (int d = 0; d < 32; d++) {
    float t = scale > 0.f ? (x[d] - mn) / scale : 0.f;
    float q = fminf(fmaxf(rintf(t), 0.f), 15.f);
    dst[vidx(s, j * 32 + d)] = (bf16_t)(q * scale + mn);
  }
}

// ======================================================================
// RoPE Q/K_new + scatter into Qa (rows) and Kc/Vc (fragment layout).
// ======================================================================
__global__ __launch_bounds__(128) void rope_scatter(
    const bf16_t* __restrict__ Y, const int* __restrict__ posids,
    bf16_t* __restrict__ Qa, bf16_t* __restrict__ Kc, bf16_t* __restrict__ Vc)
{
  const int i = blockIdx.x;
  const int u = blockIdx.y;
  const int d = threadIdx.x;

  if (u >= 40) {
    const int hv = u - 40;
    float v = (float)Y[(size_t)i * 6144 + 5120 + hv * HD_ + d];
    Vc[(size_t)hv * (KVL_ * HD_) + vidx(PAST_ + i, d)] = (bf16_t)v;
    return;
  }
  const int pos = posids[i];
  const int fi = d & 63;
  const float inv_freq = exp2f(-(float)fi * 0.2076205059304601f);
  const float ang = (float)pos * inv_freq;
  float sn, cs;
  sincosf(ang, &sn, &cs);

  if (u < 32) {
    const bf16_t* src = &Y[(size_t)i * 6144 + u * HD_];
    float x  = (float)src[d];
    float xo = (float)src[d ^ 64];
    float rot = (d < 64) ? -xo : xo;
    Qa[((size_t)u * QL_ + i) * HD_ + d] = (bf16_t)((x * cs + rot * sn) * QSCALE);
  } else {
    const int hk = u - 32;
    const bf16_t* src = &Y[(size_t)i * 6144 + 4096 + hk * HD_];
    float x  = (float)src[d];
    float xo = (float)src[d ^ 64];
    float rot = (d < 64) ? -xo : xo;
    Kc[(size_t)hk * (KVL_ * HD_) + kidx(PAST_ + i, d)] = (bf16_t)(x * cs + rot * sn);
  }
}

// ======================================================================
// Flash attention: fragment-contiguous KV staged ONCE per block into LDS
// via global_load_lds (lane-contiguous, no swizzle needed), shared by all
// 4 waves. 1-D grid 1024 blocks, idx%8 = kvh pins each KV head's readers
// to one XCD (KV stays L2-resident). No-max softmax (Q prescaled), l via
// ones-B-fragment MFMA. Pw wave-private (no barrier for transpose).
// LDS 48 KB -> 3 blocks/CU.
// ======================================================================
__global__ __launch_bounds__(256, 3) void attn_kernel(
    const bf16_t* __restrict__ Qa, const bf16_t* __restrict__ Kc,
    const bf16_t* __restrict__ Vc, bf16_t* __restrict__ Opart,
    float* __restrict__ ML)
{
  __shared__ bf16_t Ks[64 * HD_];     // 16 KB, fragment-contiguous
  __shared__ bf16_t Vs[64 * HD_];     // 16 KB
  __shared__ bf16_t Pw[4][32 * 64];   // per-wave P scratch, swizzled

  const int tid = threadIdx.x, w = tid >> 6, lane = tid & 63;
  const int lm = lane & 15, quad = lane >> 4;
  const int idx = blockIdx.x;
  const int grp = idx & 63;          // sp*8 + kvh
  const int inner = idx >> 6;        // qt*4 + qh
  const int sp = grp >> 3, kvh = grp & 7;
  const int h = kvh * 4 + (inner & 3);
  const int qt = inner >> 2;
  const int qw = qt * 128 + w * 32;

  bf16x8 ones8;
#pragma unroll
  for (int j = 0; j < 8; j++) ones8[j] = (bf16_t)1.0f;

  bf16x8 qf[2][4];
#pragma unroll
  for (int mt = 0; mt < 2; mt++)
#pragma unroll
    for (int kb = 0; kb < 4; kb++)
      qf[mt][kb] = *(const bf16x8*)&Qa[((size_t)h * QL_ + qw + mt * 16 + lm) * HD_ + kb * 32 + quad * 8];

  f32x4 o[2][8], ol[2];
#pragma unroll
  for (int mt = 0; mt < 2; mt++) {
    ol[mt] = f32x4{0.f, 0.f, 0.f, 0.f};
#pragma unroll
    for (int i = 0; i < 8; i++) o[mt][i] = f32x4{0.f, 0.f, 0.f, 0.f};
  }

  const bf16_t* Kb = Kc + (size_t)kvh * (KVL_ * HD_);
  const bf16_t* Vb = Vc + (size_t)kvh * (KVL_ * HD_);

  const int T = 58 + 2 * qt;
  const int t0 = sp * T / NSPLIT;
  const int t1 = (sp + 1) * T / NSPLIT;

  for (int it = t0; it < t1; ++it) {
    const bf16_t* kt = Kb + (size_t)it * 8192;
    const bf16_t* vt = Vb + (size_t)it * 8192;
    // stage K,V tile (once per block; lane-contiguous fragment order)
#pragma unroll
    for (int j = 0; j < 4; j++) {
      ASYNC16(kt + (size_t)(tid + j * 256) * 8, &Ks[(tid + j * 256) * 8]);
      ASYNC16(vt + (size_t)(tid + j * 256) * 8, &Vs[(tid + j * 256) * 8]);
    }
    __syncthreads();

    const bool needmask = (it >= T - 2);
    const int kv0 = it * 64;

    // S = Q K^T ; exp2 -> Pw
#pragma unroll
    for (int nt = 0; nt < 4; nt++) {
      f32x4 s0 = f32x4{0.f, 0.f, 0.f, 0.f};
      f32x4 s1 = f32x4{0.f, 0.f, 0.f, 0.f};
#pragma unroll
      for (int kb = 0; kb < 4; kb++) {
        bf16x8 kf = *(const bf16x8*)&Ks[((nt * 4 + kb) * 64 + lane) * 8];
        s0 = mfma16(qf[0][kb], kf, s0);
        s1 = mfma16(qf[1][kb], kf, s1);
      }
      if (needmask) {
        const int col = kv0 + nt * 16 + lm;
#pragma unroll
        for (int r = 0; r < 4; r++) {
          if (col > PAST_ + qw + quad * 4 + r)      s0[r] = -1e30f;
          if (col > PAST_ + qw + 16 + quad * 4 + r) s1[r] = -1e30f;
        }
      }
#pragma unroll
      for (int r = 0; r < 4; r++) {
        const int row0 = quad * 4 + r;
        const int sg0 = ((nt * 2) + (lm >> 3)) ^ (row0 & 7);
        Pw[w][row0 * 64 + sg0 * 8 + (lm & 7)] = (bf16_t)exp2f(s0[r]);
        const int row1 = 16 + quad * 4 + r;
        const int sg1 = ((nt * 2) + (lm >> 3)) ^ (row1 & 7);
        Pw[w][row1 * 64 + sg1 * 8 + (lm & 7)] = (bf16_t)exp2f(s1[r]);
      }
    }

    // O += P V
    bf16x8 pf[2][2];
#pragma unroll
    for (int mt = 0; mt < 2; mt++)
#pragma unroll
      for (int kb = 0; kb < 2; kb++) {
        const int r = mt * 16 + lm;
        pf[mt][kb] = *(const bf16x8*)&Pw[w][r * 64 + (((kb * 4 + quad) ^ (r & 7)) * 8)];
      }
#pragma unroll
    for (int dt = 0; dt < 8; dt++) {
#pragma unroll
      for (int kb = 0; kb < 2; kb++) {
        bf16x8 vf = *(const bf16x8*)&Vs[((dt * 2 + kb) * 64 + lane) * 8];
        o[0][dt] = mfma16(pf[0][kb], vf, o[0][dt]);
        o[1][dt] = mfma16(pf[1][kb], vf, o[1][dt]);
      }
    }
#pragma unroll
    for (int kb = 0; kb < 2; kb++) {
      ol[0] = mfma16(pf[0][kb], ones8, ol[0]);
      ol[1] = mfma16(pf[1][kb], ones8, ol[1]);
    }
    __syncthreads();   // all waves done with Ks/Vs before next staging
  }

  // epilogue: un-normalized partial O + l
  const size_t pbase = ((size_t)(sp * NH_ + h) * QL_ + qw);
#pragma unroll
  for (int mt = 0; mt < 2; mt++) {
#pragma unroll
    for (int dt = 0; dt < 8; dt++)
#pragma unroll
      for (int r = 0; r < 4; r++)
        Opart[(pbase + mt * 16 + quad * 4 + r) * HD_ + dt * 16 + lm] = (bf16_t)o[mt][dt][r];
  }
  if (lm == 0) {
#pragma unroll
    for (int mt = 0; mt < 2; mt++)
#pragma unroll
      for (int r = 0; r < 4; r++)
        ML[pbase + mt * 16 + quad * 4 + r] = ol[mt][r];
  }
}

// ======================================================================
// Combine split partials: O = sum_s O_s / sum_s l_s
// ======================================================================
__global__ __launch_bounds__(128) void combine_kernel(
    const bf16_t* __restrict__ Opart, const float* __restrict__ ML,
    bf16_t* __restrict__ AttnO)
{
  const int q = blockIdx.x, h = blockIdx.y, d = threadIdx.x;
  float lsum = 0.f, o = 0.f;
#pragma unroll
  for (int s = 0; s < NSPLIT; s++) {
    const size_t base = (size_t)(s * NH_ + h) * QL_ + q;
    lsum += ML[base];
    o += (float)Opart[base * HD_ + d];
  }
  AttnO[(size_t)q * (NH_ * HD_) + h * HD_ + d] = (bf16_t)(o / lsum);
}

// ======================================================================
extern "C" void kernel_launch(void* const* d_in, const int* in_sizes, int n_in,
                              void* d_out, int out_size, void* d_ws, size_t ws_size,
                              hipStream_t stream)
{
  (void)in_sizes; (void)n_in; (void)out_size; (void)ws_size;
  const float* hidden = (const float*)d_in[0];
  const float* past_k = (const float*)d_in[1];
  const float* past_v = (const float*)d_in[2];
  const float* wq  = (const float*)d_in[3];
  const float* wk  = (const float*)d_in[4];
  const float* wv  = (const float*)d_in[5];
  const float* wo  = (const float*)d_in[6];
  const int*   pos = (const int*)d_in[7];

  char* p = (char*)d_ws;
  bf16_t* Y     = (bf16_t*)p;  p += (size_t)QL_ * 6144 * 2;
  bf16_t* Qa    = (bf16_t*)p;  p += (size_t)QL_ * NH_ * HD_ * 2;
  bf16_t* Kc    = (bf16_t*)p;  p += (size_t)NKV_ * KVL_ * HD_ * 2;
  bf16_t* Vc    = (bf16_t*)p;  p += (size_t)NKV_ * HD_ * KVL_ * 2;
  bf16_t* AttnO = (bf16_t*)p;  p += (size_t)QL_ * NH_ * HD_ * 2;
  bf16_t* Opart = (bf16_t*)p;  p += (size_t)NSPLIT * NH_ * QL_ * HD_ * 2;
  float*  ML    = (float*)p;   p += (size_t)NSPLIT * NH_ * QL_ * 4;
  bf16_t* Hbf   = (bf16_t*)p;  p += (size_t)QL_ * HID_ * 2;

  const int CVB = 1024;
  cvt_f32_bf16<<<CVB, 256, 0, stream>>>(hidden, Hbf,  QL_ * HID_ / 4);
  dequant_key  <<<dim3(PAST_ / 32, NKV_), dim3(128), 0, stream>>>(past_k, Kc);
  dequant_value<<<dim3(PAST_ / 64, NKV_), dim3(256), 0, stream>>>(past_v, Vc);

  // QKV projection: B-operand = raw fp32 weights, converted inline
  gemm_bt<false><<<dim3(6144 / 64, QL_ / 64), dim3(256), 0, stream>>>(
      Hbf, wq, wk, wv, 4096, 5120, (void*)Y, HID_, HID_, HID_, 6144);

  rope_scatter<<<dim3(QL_, 48), dim3(128), 0, stream>>>(Y, pos, Qa, Kc, Vc);
  attn_kernel <<<dim3(16 * 64), dim3(256), 0, stream>>>(Qa, Kc, Vc, Opart, ML);
  combine_kernel<<<dim3(QL_, NH_), dim3(128), 0, stream>>>(Opart, ML, AttnO);

  // O projection: B-operand = raw fp32 wo, converted inline
  gemm_bt<true><<<dim3(4096 / 64, QL_ / 64), dim3(256), 0, stream>>>(
      AttnO, wo, wo, wo, 1 << 30, 1 << 30, d_out,
      NH_ * HD_, NH_ * HD_, HID_, HID_);
}

// Round 2
// 384.766 us; speedup vs baseline: 1.0138x; 1.0138x over previous
//
#include <hip/hip_runtime.h>
#include <hip/hip_bf16.h>

typedef __bf16 bf16_t;
typedef __bf16 bf16x4 __attribute__((ext_vector_type(4)));
typedef __bf16 bf16x8 __attribute__((ext_vector_type(8)));
typedef float  f32x4  __attribute__((ext_vector_type(4)));

static __device__ __forceinline__ f32x4 mfma16(bf16x8 a, bf16x8 b, f32x4 c) {
  return __builtin_amdgcn_mfma_f32_16x16x32_bf16(a, b, c, 0, 0, 0);
}

typedef const __attribute__((address_space(1))) void* gas_t;
typedef __attribute__((address_space(3))) void* las_t;
#define ASYNC16(g, l) __builtin_amdgcn_global_load_lds((gas_t)(g), (las_t)(l), 16, 0, 0)

// Problem constants
#define QL_   512
#define HID_  4096
#define NH_   32
#define NKV_  8
#define HD_   128
#define PAST_ 3584
#define KVL_  4096   // PAST_ + QL_
#define NSPLIT 8     // attention kv-split factor

// Q prescale: log2(e)/sqrt(128) -> softmax via raw exp2, no max subtraction
#define QSCALE 0.12751750152134056f

// K fragment-layout index (kv-tiles of 64, MFMA B-operand contiguous)
static __device__ __forceinline__ size_t kidx(int s, int d) {
  return ((size_t)(((s >> 6) * 4 + ((s >> 4) & 3)) * 4 + (d >> 5))) * 512
         + ((((d >> 3) & 3) * 16 + (s & 15)) * 8) + (d & 7);
}
// V fragment-layout index (PV B-operand: out-col = d, contraction = kv)
static __device__ __forceinline__ size_t vidx(int s, int d) {
  return ((size_t)(((s >> 6) * 8 + (d >> 4)) * 2 + ((s >> 5) & 1))) * 512
         + (((((s >> 3) & 3) * 16 + (d & 15)) * 8)) + (s & 7);
}

static __device__ __forceinline__ bf16x8 cvt8(float4 a, float4 b) {
  bf16x8 o;
  o[0] = (bf16_t)a.x; o[1] = (bf16_t)a.y; o[2] = (bf16_t)a.z; o[3] = (bf16_t)a.w;
  o[4] = (bf16_t)b.x; o[5] = (bf16_t)b.y; o[6] = (bf16_t)b.z; o[7] = (bf16_t)b.w;
  return o;
}

// ======================================================================
// fp32 -> bf16 streaming convert (n4 = element count / 4)
// ======================================================================
__global__ __launch_bounds__(256) void cvt_f32_bf16(
    const float* __restrict__ src, bf16_t* __restrict__ dst, int n4)
{
  int i = blockIdx.x * 256 + threadIdx.x;
  const int stride = gridDim.x * 256;
  for (; i < n4; i += stride) {
    float4 f = ((const float4*)src)[i];
    bf16x4 o;
    o[0] = (bf16_t)f.x; o[1] = (bf16_t)f.y; o[2] = (bf16_t)f.z; o[3] = (bf16_t)f.w;
    ((bf16x4*)dst)[i] = o;
  }
}

// ======================================================================
// GEMM: C[M,N] = A[M,K] @ B[N,K]^T.  A bf16 (global_load_lds),
// B fp32 converted inline during reg-staging.
// Schedule: B(k+1) regs are consumed at the TOP of iteration k -- right
// after __syncthreads, whose vmcnt(0) drain already paid for them (zero
// extra wait). B(k+2) loads are issued immediately after, giving them a
// full compute phase + barrier in flight. Single drain point per iter
// (round-1 version paid a second serialized mid-iteration stall).
// BM=BN=64, BK=64; 4 waves 2x2, double-buffered LDS.
// ======================================================================
template<bool C_F32>
__global__ __launch_bounds__(256) void gemm_bt(
    const bf16_t* __restrict__ A,
    const float* __restrict__ B0, const float* __restrict__ B1,
    const float* __restrict__ B2, int nsplit1, int nsplit2,
    void* __restrict__ Cptr, int K, int lda, int ldb, int ldc)
{
  constexpr int BM = 64, BN = 64, BK = 64;
  __shared__ bf16_t As[2][BM * BK];
  __shared__ bf16_t Bs[2][BN * BK];

  const int tid = threadIdx.x;
  const int w = tid >> 6, lane = tid & 63;
  const int lm = lane & 15, quad = lane >> 4;
  const int wr = w >> 1, wc = w & 1;
  const int bm0 = blockIdx.y * BM, bn0 = blockIdx.x * BN;

  const float* Bseg; int bn_loc;
  if (bn0 < nsplit1)      { Bseg = B0; bn_loc = bn0; }
  else if (bn0 < nsplit2) { Bseg = B1; bn_loc = bn0 - nsplit1; }
  else                    { Bseg = B2; bn_loc = bn0 - nsplit2; }

  int sid[2], soff[2];
#pragma unroll
  for (int j = 0; j < 2; j++) {
    sid[j] = j * 256 + tid;
    const int r = sid[j] >> 3, c = sid[j] & 7;
    soff[j] = r * 64 + (c ^ (r & 7)) * 8;
  }
  const bf16_t* Abase = A + (size_t)bm0 * lda;
  const float* Bbase = Bseg + (size_t)bn_loc * ldb;

  f32x4 acc[2][2];
#pragma unroll
  for (int i = 0; i < 2; i++)
#pragma unroll
    for (int j = 0; j < 2; j++) acc[i][j] = f32x4{0.f, 0.f, 0.f, 0.f};

  float4 bB[2][2];
  // prologue: B(0) -> regs -> Bs[0]; A(0) via global_load_lds; B(1) -> regs
#pragma unroll
  for (int j = 0; j < 2; j++) {
    const int r = soff[j] >> 6, c = soff[j] & 63;
    const float* bp = Bbase + (size_t)r * ldb + c;
    bB[j][0] = *(const float4*)bp;
    bB[j][1] = *(const float4*)(bp + 4);
  }
#pragma unroll
  for (int j = 0; j < 2; j++) {
    const int r = soff[j] >> 6, c = soff[j] & 63;
    ASYNC16(Abase + (size_t)r * lda + c, &As[0][sid[j] * 8]);
  }
#pragma unroll
  for (int j = 0; j < 2; j++)
    *(bf16x8*)&Bs[0][sid[j] * 8] = cvt8(bB[j][0], bB[j][1]);
  if (BK < K) {
#pragma unroll
    for (int j = 0; j < 2; j++) {
      const int r = soff[j] >> 6, c = soff[j] & 63;
      const float* bp = Bbase + (size_t)r * ldb + BK + c;
      bB[j][0] = *(const float4*)bp;
      bB[j][1] = *(const float4*)(bp + 4);
    }
  }

  int cur = 0;
  for (int k0 = 0; k0 < K; k0 += BK) {
    __syncthreads();   // single drain: pays for B(k+1) regs AND A(k) LDS
    const bool pre = (k0 + BK < K);
    if (pre) {
      // B(k+1) regs complete (drained) -> write to LDS with zero wait
#pragma unroll
      for (int j = 0; j < 2; j++)
        *(bf16x8*)&Bs[cur ^ 1][sid[j] * 8] = cvt8(bB[j][0], bB[j][1]);
      // issue B(k+2): in flight across the whole compute phase
      if (k0 + 2 * BK < K) {
#pragma unroll
        for (int j = 0; j < 2; j++) {
          const int r = soff[j] >> 6, c = soff[j] & 63;
          const float* bp = Bbase + (size_t)r * ldb + k0 + 2 * BK + c;
          bB[j][0] = *(const float4*)bp;
          bB[j][1] = *(const float4*)(bp + 4);
        }
      }
      // issue A(k+1)
#pragma unroll
      for (int j = 0; j < 2; j++) {
        const int r = soff[j] >> 6, c = soff[j] & 63;
        ASYNC16(Abase + (size_t)r * lda + k0 + BK + c, &As[cur ^ 1][sid[j] * 8]);
      }
    }
#pragma unroll
    for (int kb = 0; kb < 2; kb++) {
      bf16x8 af[2], bf[2];
#pragma unroll
      for (int mt = 0; mt < 2; mt++) {
        const int r = wr * 32 + mt * 16 + lm;
        af[mt] = *(const bf16x8*)&As[cur][r * 64 + (((kb * 4 + quad) ^ (r & 7)) * 8)];
      }
#pragma unroll
      for (int nt = 0; nt < 2; nt++) {
        const int r = wc * 32 + nt * 16 + lm;
        bf[nt] = *(const bf16x8*)&Bs[cur][r * 64 + (((kb * 4 + quad) ^ (r & 7)) * 8)];
      }
#pragma unroll
      for (int mt = 0; mt < 2; mt++)
#pragma unroll
        for (int nt = 0; nt < 2; nt++)
          acc[mt][nt] = mfma16(af[mt], bf[nt], acc[mt][nt]);
    }
    cur ^= 1;
  }

#pragma unroll
  for (int mt = 0; mt < 2; mt++) {
#pragma unroll
    for (int nt = 0; nt < 2; nt++) {
      const int row = bm0 + wr * 32 + mt * 16 + quad * 4;
      const int col = bn0 + wc * 32 + nt * 16 + lm;
#pragma unroll
      for (int r = 0; r < 4; r++) {
        if constexpr (C_F32)
          ((float*)Cptr)[(size_t)(row + r) * ldc + col] = acc[mt][nt][r];
        else
          ((bf16_t*)Cptr)[(size_t)(row + r) * ldc + col] = (bf16_t)acc[mt][nt][r];
      }
    }
  }
}

// ======================================================================
// Dequant past K -> fragment-contiguous Kc.
// ======================================================================
__global__ __launch_bounds__(128) void dequant_key(
    const float* __restrict__ pk, bf16_t* __restrict__ Kc)
{
  const int g = blockIdx.x, h = blockIdx.y, d = threadIdx.x;
  const float* src = pk + ((size_t)h * PAST_ + g * 32) * HD_ + d;
  float x[32];
  float mn = 1e30f, mx = -1e30f;
#pragma unroll
  for (int s = 0; s < 32; s++) {
    x[s] = src[(size_t)s * HD_];
    mn = fminf(mn, x[s]); mx = fmaxf(mx, x[s]);
  }
  float scale = (mx - mn) / 15.0f;
  bf16_t* dst = Kc + (size_t)h * (KVL_ * HD_);
#pragma unroll
  for (int s = 0; s < 32; s++) {
    float t = scale > 0.f ? (x[s] - mn) / scale : 0.f;
    float q = fminf(fmaxf(rintf(t), 0.f), 15.f);
    dst[kidx(g * 32 + s, d)] = (bf16_t)(q * scale + mn);
  }
}

// ======================================================================
// Dequant past V -> fragment-contiguous Vc.
// ======================================================================
__global__ __launch_bounds__(256) void dequant_value(
    const float* __restrict__ pv, bf16_t* __restrict__ Vc)
{
  const int sc = blockIdx.x, h = blockIdx.y;
  const int j = threadIdx.x >> 6, lane = threadIdx.x & 63;
  const int s = sc * 64 + lane;
  const float* src = pv + ((size_t)h * PAST_ + s) * HD_ + j * 32;
  float x[32];
  float mn = 1e30f, mx = -1e30f;
#pragma unroll
  for (int q4 = 0; q4 < 8; q4++) {
    float4 f = ((const float4*)src)[q4];
    x[q4*4+0] = f.x; x[q4*4+1] = f.y; x[q4*4+2] = f.z; x[q4*4+3] = f.w;
    mn = fminf(fminf(mn, fminf(f.x, f.y)), fminf(f.z, f.w));
    mx = fmaxf(fmaxf(mx, fmaxf(f.x, f.y)), fmaxf(f.z, f.w));
  }
  float scale = (mx - mn) / 15.0f;
  bf16_t* dst = Vc + (size_t)h * (KVL_ * HD_);
#pragma unroll
  for (int d = 0; d < 32; d++) {
    float t = scale > 0.f ? (x[d] - mn) / scale : 0.f;
    float q = fminf(fmaxf(rintf(t), 0.f), 15.f);
    dst[vidx(s, j * 32 + d)] = (bf16_t)(q * scale + mn);
  }
}

// ======================================================================
// RoPE Q/K_new + scatter into Qa (rows) and Kc/Vc (fragment layout).
// ======================================================================
__global__ __launch_bounds__(128) void rope_scatter(
    const bf16_t* __restrict__ Y, const int* __restrict__ posids,
    bf16_t* __restrict__ Qa, bf16_t* __restrict__ Kc, bf16_t* __restrict__ Vc)
{
  const int i = blockIdx.x;
  const int u = blockIdx.y;
  const int d = threadIdx.x;

  if (u >= 40) {
    const int hv = u - 40;
    float v = (float)Y[(size_t)i * 6144 + 5120 + hv * HD_ + d];
    Vc[(size_t)hv * (KVL_ * HD_) + vidx(PAST_ + i, d)] = (bf16_t)v;
    return;
  }
  const int pos = posids[i];
  const int fi = d & 63;
  const float inv_freq = exp2f(-(float)fi * 0.2076205059304601f);
  const float ang = (float)pos * inv_freq;
  float sn, cs;
  sincosf(ang, &sn, &cs);

  if (u < 32) {
    const bf16_t* src = &Y[(size_t)i * 6144 + u * HD_];
    float x  = (float)src[d];
    float xo = (float)src[d ^ 64];
    float rot = (d < 64) ? -xo : xo;
    Qa[((size_t)u * QL_ + i) * HD_ + d] = (bf16_t)((x * cs + rot * sn) * QSCALE);
  } else {
    const int hk = u - 32;
    const bf16_t* src = &Y[(size_t)i * 6144 + 4096 + hk * HD_];
    float x  = (float)src[d];
    float xo = (float)src[d ^ 64];
    float rot = (d < 64) ? -xo : xo;
    Kc[(size_t)hk * (KVL_ * HD_) + kidx(PAST_ + i, d)] = (bf16_t)(x * cs + rot * sn);
  }
}

// ======================================================================
// Flash attention: fragment-contiguous KV staged ONCE per block into LDS
// via global_load_lds (lane-contiguous, no swizzle needed), shared by all
// 4 waves. 1-D grid 1024 blocks, idx%8 = kvh pins each KV head's readers
// to one XCD (KV stays L2-resident). No-max softmax (Q prescaled), l via
// ones-B-fragment MFMA. Pw wave-private (no barrier for transpose).
// LDS 48 KB -> 3 blocks/CU.
// ======================================================================
__global__ __launch_bounds__(256, 3) void attn_kernel(
    const bf16_t* __restrict__ Qa, const bf16_t* __restrict__ Kc,
    const bf16_t* __restrict__ Vc, bf16_t* __restrict__ Opart,
    float* __restrict__ ML)
{
  __shared__ bf16_t Ks[64 * HD_];     // 16 KB, fragment-contiguous
  __shared__ bf16_t Vs[64 * HD_];     // 16 KB
  __shared__ bf16_t Pw[4][32 * 64];   // per-wave P scratch, swizzled

  const int tid = threadIdx.x, w = tid >> 6, lane = tid & 63;
  const int lm = lane & 15, quad = lane >> 4;
  const int idx = blockIdx.x;
  const int grp = idx & 63;          // sp*8 + kvh
  const int inner = idx >> 6;        // qt*4 + qh
  const int sp = grp >> 3, kvh = grp & 7;
  const int h = kvh * 4 + (inner & 3);
  const int qt = inner >> 2;
  const int qw = qt * 128 + w * 32;

  bf16x8 ones8;
#pragma unroll
  for (int j = 0; j < 8; j++) ones8[j] = (bf16_t)1.0f;

  bf16x8 qf[2][4];
#pragma unroll
  for (int mt = 0; mt < 2; mt++)
#pragma unroll
    for (int kb = 0; kb < 4; kb++)
      qf[mt][kb] = *(const bf16x8*)&Qa[((size_t)h * QL_ + qw + mt * 16 + lm) * HD_ + kb * 32 + quad * 8];

  f32x4 o[2][8], ol[2];
#pragma unroll
  for (int mt = 0; mt < 2; mt++) {
    ol[mt] = f32x4{0.f, 0.f, 0.f, 0.f};
#pragma unroll
    for (int i = 0; i < 8; i++) o[mt][i] = f32x4{0.f, 0.f, 0.f, 0.f};
  }

  const bf16_t* Kb = Kc + (size_t)kvh * (KVL_ * HD_);
  const bf16_t* Vb = Vc + (size_t)kvh * (KVL_ * HD_);

  const int T = 58 + 2 * qt;
  const int t0 = sp * T / NSPLIT;
  const int t1 = (sp + 1) * T / NSPLIT;

  for (int it = t0; it < t1; ++it) {
    const bf16_t* kt = Kb + (size_t)it * 8192;
    const bf16_t* vt = Vb + (size_t)it * 8192;
    // stage K,V tile (once per block; lane-contiguous fragment order)
#pragma unroll
    for (int j = 0; j < 4; j++) {
      ASYNC16(kt + (size_t)(tid + j * 256) * 8, &Ks[(tid + j * 256) * 8]);
      ASYNC16(vt + (size_t)(tid + j * 256) * 8, &Vs[(tid + j * 256) * 8]);
    }
    __syncthreads();

    const bool needmask = (it >= T - 2);
    const int kv0 = it * 64;

    // S = Q K^T ; exp2 -> Pw
#pragma unroll
    for (int nt = 0; nt < 4; nt++) {
      f32x4 s0 = f32x4{0.f, 0.f, 0.f, 0.f};
      f32x4 s1 = f32x4{0.f, 0.f, 0.f, 0.f};
#pragma unroll
      for (int kb = 0; kb < 4; kb++) {
        bf16x8 kf = *(const bf16x8*)&Ks[((nt * 4 + kb) * 64 + lane) * 8];
        s0 = mfma16(qf[0][kb], kf, s0);
        s1 = mfma16(qf[1][kb], kf, s1);
      }
      if (needmask) {
        const int col = kv0 + nt * 16 + lm;
#pragma unroll
        for (int r = 0; r < 4; r++) {
          if (col > PAST_ + qw + quad * 4 + r)      s0[r] = -1e30f;
          if (col > PAST_ + qw + 16 + quad * 4 + r) s1[r] = -1e30f;
        }
      }
#pragma unroll
      for (int r = 0; r < 4; r++) {
        const int row0 = quad * 4 + r;
        const int sg0 = ((nt * 2) + (lm >> 3)) ^ (row0 & 7);
        Pw[w][row0 * 64 + sg0 * 8 + (lm & 7)] = (bf16_t)exp2f(s0[r]);
        const int row1 = 16 + quad * 4 + r;
        const int sg1 = ((nt * 2) + (lm >> 3)) ^ (row1 & 7);
        Pw[w][row1 * 64 + sg1 * 8 + (lm & 7)] = (bf16_t)exp2f(s1[r]);
      }
    }

    // O += P V
    bf16x8 pf[2][2];
#pragma unroll
    for (int mt = 0; mt < 2; mt++)
#pragma unroll
      for (int kb = 0; kb < 2; kb++) {
        const int r = mt * 16 + lm;
        pf[mt][kb] = *(const bf16x8*)&Pw[w][r * 64 + (((kb * 4 + quad) ^ (r & 7)) * 8)];
      }
#pragma unroll
    for (int dt = 0; dt < 8; dt++) {
#pragma unroll
      for (int kb = 0; kb < 2; kb++) {
        bf16x8 vf = *(const bf16x8*)&Vs[((dt * 2 + kb) * 64 + lane) * 8];
        o[0][dt] = mfma16(pf[0][kb], vf, o[0][dt]);
        o[1][dt] = mfma16(pf[1][kb], vf, o[1][dt]);
      }
    }
#pragma unroll
    for (int kb = 0; kb < 2; kb++) {
      ol[0] = mfma16(pf[0][kb], ones8, ol[0]);
      ol[1] = mfma16(pf[1][kb], ones8, ol[1]);
    }
    __syncthreads();   // all waves done with Ks/Vs before next staging
  }

  // epilogue: un-normalized partial O + l
  const size_t pbase = ((size_t)(sp * NH_ + h) * QL_ + qw);
#pragma unroll
  for (int mt = 0; mt < 2; mt++) {
#pragma unroll
    for (int dt = 0; dt < 8; dt++)
#pragma unroll
      for (int r = 0; r < 4; r++)
        Opart[(pbase + mt * 16 + quad * 4 + r) * HD_ + dt * 16 + lm] = (bf16_t)o[mt][dt][r];
  }
  if (lm == 0) {
#pragma unroll
    for (int mt = 0; mt < 2; mt++)
#pragma unroll
      for (int r = 0; r < 4; r++)
        ML[pbase + mt * 16 + quad * 4 + r] = ol[mt][r];
  }
}

// ======================================================================
// Combine split partials: O = sum_s O_s / sum_s l_s
// ======================================================================
__global__ __launch_bounds__(128) void combine_kernel(
    const bf16_t* __restrict__ Opart, const float* __restrict__ ML,
    bf16_t* __restrict__ AttnO)
{
  const int q = blockIdx.x, h = blockIdx.y, d = threadIdx.x;
  float lsum = 0.f, o = 0.f;
#pragma unroll
  for (int s = 0; s < NSPLIT; s++) {
    const size_t base = (size_t)(s * NH_ + h) * QL_ + q;
    lsum += ML[base];
    o += (float)Opart[base * HD_ + d];
  }
  AttnO[(size_t)q * (NH_ * HD_) + h * HD_ + d] = (bf16_t)(o / lsum);
}

// ======================================================================
extern "C" void kernel_launch(void* const* d_in, const int* in_sizes, int n_in,
                              void* d_out, int out_size, void* d_ws, size_t ws_size,
                              hipStream_t stream)
{
  (void)in_sizes; (void)n_in; (void)out_size; (void)ws_size;
  const float* hidden = (const float*)d_in[0];
  const float* past_k = (const float*)d_in[1];
  const float* past_v = (const float*)d_in[2];
  const float* wq  = (const float*)d_in[3];
  const float* wk  = (const float*)d_in[4];
  const float* wv  = (const float*)d_in[5];
  const float* wo  = (const float*)d_in[6];
  const int*   pos = (const int*)d_in[7];

  char* p = (char*)d_ws;
  bf16_t* Y     = (bf16_t*)p;  p += (size_t)QL_ * 6144 * 2;
  bf16_t* Qa    = (bf16_t*)p;  p += (size_t)QL_ * NH_ * HD_ * 2;
  bf16_t* Kc    = (bf16_t*)p;  p += (size_t)NKV_ * KVL_ * HD_ * 2;
  bf16_t* Vc    = (bf16_t*)p;  p += (size_t)NKV_ * HD_ * KVL_ * 2;
  bf16_t* AttnO = (bf16_t*)p;  p += (size_t)QL_ * NH_ * HD_ * 2;
  bf16_t* Opart = (bf16_t*)p;  p += (size_t)NSPLIT * NH_ * QL_ * HD_ * 2;
  float*  ML    = (float*)p;   p += (size_t)NSPLIT * NH_ * QL_ * 4;
  bf16_t* Hbf   = (bf16_t*)p;  p += (size_t)QL_ * HID_ * 2;

  const int CVB = 1024;
  cvt_f32_bf16<<<CVB, 256, 0, stream>>>(hidden, Hbf,  QL_ * HID_ / 4);
  dequant_key  <<<dim3(PAST_ / 32, NKV_), dim3(128), 0, stream>>>(past_k, Kc);
  dequant_value<<<dim3(PAST_ / 64, NKV_), dim3(256), 0, stream>>>(past_v, Vc);

  // QKV projection: B-operand = raw fp32 weights, converted inline
  gemm_bt<false><<<dim3(6144 / 64, QL_ / 64), dim3(256), 0, stream>>>(
      Hbf, wq, wk, wv, 4096, 5120, (void*)Y, HID_, HID_, HID_, 6144);

  rope_scatter<<<dim3(QL_, 48), dim3(128), 0, stream>>>(Y, pos, Qa, Kc, Vc);
  attn_kernel <<<dim3(16 * 64), dim3(256), 0, stream>>>(Qa, Kc, Vc, Opart, ML);
  combine_kernel<<<dim3(QL_, NH_), dim3(128), 0, stream>>>(Opart, ML, AttnO);

  // O projection: B-operand = raw fp32 wo, converted inline
  gemm_bt<true><<<dim3(4096 / 64, QL_ / 64), dim3(256), 0, stream>>>(
      AttnO, wo, wo, wo, 1 << 30, 1 << 30, d_out,
      NH_ * HD_, NH_ * HD_, HID_, HID_);
}